// Round 3
// baseline (1218.387 us; speedup 1.0000x reference)
//
#include <hip/hip_runtime.h>
#include <math.h>

// Problem constants (from reference): B=4096, Z=50000, E=300, K=5
#define B_ 4096
#define Z_ 50000
#define E_ 300
#define K_ 5
#define NT 256   // threads for topk/attn kernel
#define BT 16    // batch tile for mapping kernel

// ---------------------------------------------------------------------------
// Kernel 1: aligned_ctx[b][e] = sum_j ctx[b][j] * W_map[e][j]   (ctx @ W^T)
// One block computes BT=16 rows of aligned_ctx. ctx tile staged in LDS
// (wave-uniform broadcast reads), W_map rows streamed as float4 (L2-resident:
// 360 KB). 300 active threads of 320.
// ---------------------------------------------------------------------------
__global__ __launch_bounds__(320) void map_kernel(const float* __restrict__ ctx,
                                                  const float* __restrict__ Wm,
                                                  float* __restrict__ aligned) {
  __shared__ __align__(16) float sctx[BT][E_];
  const int b0 = blockIdx.x * BT;
  for (int i = threadIdx.x; i < BT * E_; i += 320) {
    const int bb = i / E_;
    const int j = i - bb * E_;
    sctx[bb][j] = ctx[(size_t)(b0 + bb) * E_ + j];
  }
  __syncthreads();
  const int e = threadIdx.x;
  if (e < E_) {
    float acc[BT];
#pragma unroll
    for (int q = 0; q < BT; ++q) acc[q] = 0.f;
    const float4* wrow = reinterpret_cast<const float4*>(Wm + (size_t)e * E_);
    for (int j4 = 0; j4 < E_ / 4; ++j4) {
      const float4 w = wrow[j4];
#pragma unroll
      for (int q = 0; q < BT; ++q) {
        const float4 c = *reinterpret_cast<const float4*>(&sctx[q][j4 * 4]);
        acc[q] += c.x * w.x + c.y * w.y + c.z * w.z + c.w * w.w;
      }
    }
#pragma unroll
    for (int q = 0; q < BT; ++q) aligned[(size_t)(b0 + q) * E_ + e] = acc[q];
  }
}

// ---------------------------------------------------------------------------
// Kernel 2 (fused): per row b of sp_z:
//   top-5 (values desc, tie -> lower index, matching jax.lax.top_k)
//   scores_k = dot(sp_w[idx_k], aligned[b]);  attn = softmax(scores)
//   out[b] = sum_k attn_k * sp_w[idx_k];  amax[b] = argmax_k attn (first max)
// One block (256 threads) per row. sp_z streamed as float4 (coalesced, the
// 819 MB that dominates). Per-thread sorted top-5 in registers (static
// indexing only), then LDS tree merge.
// ---------------------------------------------------------------------------
__global__ __launch_bounds__(NT) void topk_attn_kernel(
    const float* __restrict__ sp_z, const float* __restrict__ sp_w,
    const float* __restrict__ aligned, float* __restrict__ outv,
    float* __restrict__ attn_out, float* __restrict__ amax_out) {
  const int b = blockIdx.x;
  const int tid = threadIdx.x;

  __shared__ __align__(16) float sal[E_];      // aligned_ctx row
  __shared__ float sval[NT * K_];              // per-thread top-5 values
  __shared__ int sidx[NT * K_];                // per-thread top-5 indices
  __shared__ float sw[K_][E_];                 // gathered topW rows
  __shared__ float sred[K_][4];                // per-wave score partials
  __shared__ float sattn[K_];                  // softmax weights

  // stage aligned_ctx row (covered by the first __syncthreads below)
  for (int e2 = tid; e2 < E_; e2 += NT) sal[e2] = aligned[(size_t)b * E_ + e2];

  // ---- per-thread streaming top-5 ----
  float tv[K_];
  int ti[K_];
#pragma unroll
  for (int p = 0; p < K_; ++p) { tv[p] = -INFINITY; ti[p] = 0x7fffffff; }

  const float4* rowz = reinterpret_cast<const float4*>(sp_z + (size_t)b * Z_);
  for (int c = tid; c < Z_ / 4; c += NT) {
    const float4 v4 = rowz[c];
    const int base = c * 4;
    const float vv[4] = {v4.x, v4.y, v4.z, v4.w};
#pragma unroll
    for (int u = 0; u < 4; ++u) {
      const float v = vv[u];
      // per-thread indices arrive in increasing order, so strict > keeps the
      // earlier (smaller) index on ties — matches jax.lax.top_k
      if (v > tv[K_ - 1]) {
        tv[K_ - 1] = v; ti[K_ - 1] = base + u;
#pragma unroll
        for (int q = K_ - 1; q > 0; --q) {
          if (tv[q] > tv[q - 1]) {  // strict: stable on equal values
            const float tf = tv[q]; tv[q] = tv[q - 1]; tv[q - 1] = tf;
            const int tt = ti[q]; ti[q] = ti[q - 1]; ti[q - 1] = tt;
          }
        }
      }
    }
  }
#pragma unroll
  for (int p = 0; p < K_; ++p) { sval[tid * K_ + p] = tv[p]; sidx[tid * K_ + p] = ti[p]; }
  __syncthreads();

  // ---- tree merge of sorted 5-lists (static register indexing only) ----
  for (int stride = NT / 2; stride >= 1; stride >>= 1) {
    if (tid < stride) {
      float av[K_], bv[K_];
      int ai[K_], bi[K_];
#pragma unroll
      for (int p = 0; p < K_; ++p) {
        av[p] = sval[tid * K_ + p]; ai[p] = sidx[tid * K_ + p];
        bv[p] = sval[(tid + stride) * K_ + p]; bi[p] = sidx[(tid + stride) * K_ + p];
      }
      // insert each element of sorted b-list into sorted a-list
#pragma unroll
      for (int p = 0; p < K_; ++p) {
        const float v = bv[p]; const int i2 = bi[p];
        if (v > av[K_ - 1] || (v == av[K_ - 1] && i2 < ai[K_ - 1])) {
          av[K_ - 1] = v; ai[K_ - 1] = i2;
#pragma unroll
          for (int q = K_ - 1; q > 0; --q) {
            const bool swp = (av[q] > av[q - 1]) ||
                             (av[q] == av[q - 1] && ai[q] < ai[q - 1]);
            if (swp) {
              const float tf = av[q]; av[q] = av[q - 1]; av[q - 1] = tf;
              const int tt = ai[q]; ai[q] = ai[q - 1]; ai[q - 1] = tt;
            }
          }
        }
      }
#pragma unroll
      for (int q = 0; q < K_; ++q) { sval[tid * K_ + q] = av[q]; sidx[tid * K_ + q] = ai[q]; }
    }
    __syncthreads();
  }
  // final row top-5 now in sval[0..4] / sidx[0..4]

  // ---- gather topW rows + partial dot with aligned row (single pass) ----
  const float* wrow[K_];
#pragma unroll
  for (int k = 0; k < K_; ++k) wrow[k] = sp_w + (size_t)sidx[k] * E_;

  float part[K_] = {0.f, 0.f, 0.f, 0.f, 0.f};
  for (int e2 = tid; e2 < E_; e2 += NT) {
    const float a = sal[e2];
#pragma unroll
    for (int k = 0; k < K_; ++k) {
      const float w = wrow[k][e2];
      sw[k][e2] = w;
      part[k] += w * a;
    }
  }

  // ---- block reduce 5 scores ----
  const int lane = tid & 63;
  const int wv = tid >> 6;
#pragma unroll
  for (int k = 0; k < K_; ++k) {
    float p = part[k];
#pragma unroll
    for (int off = 32; off >= 1; off >>= 1) p += __shfl_down(p, off, 64);
    if (lane == 0) sred[k][wv] = p;
  }
  __syncthreads();

  if (tid == 0) {
    float sc[K_];
    float m = -INFINITY;
#pragma unroll
    for (int k = 0; k < K_; ++k) {
      sc[k] = sred[k][0] + sred[k][1] + sred[k][2] + sred[k][3];
      m = fmaxf(m, sc[k]);
    }
    float s = 0.f;
#pragma unroll
    for (int k = 0; k < K_; ++k) { sc[k] = expf(sc[k] - m); s += sc[k]; }
    const float inv = 1.f / s;
    int am = 0;
    float best = -INFINITY;
#pragma unroll
    for (int k = 0; k < K_; ++k) {
      const float a = sc[k] * inv;
      sattn[k] = a;
      attn_out[(size_t)b * K_ + k] = a;
      if (a > best) { best = a; am = k; }  // strict >: first max, like argmax
    }
    amax_out[b] = (float)am;
  }
  __syncthreads();

  // ---- out[b][e] = sum_k attn_k * topW[k][e] ----
  for (int e2 = tid; e2 < E_; e2 += NT) {
    float o = 0.f;
#pragma unroll
    for (int k = 0; k < K_; ++k) o += sattn[k] * sw[k][e2];
    outv[(size_t)b * E_ + e2] = o;
  }
}

// ---------------------------------------------------------------------------
extern "C" void kernel_launch(void* const* d_in, const int* in_sizes, int n_in,
                              void* d_out, int out_size, void* d_ws, size_t ws_size,
                              hipStream_t stream) {
  const float* sp_z = (const float*)d_in[0];  // [B, Z]
  const float* sp_w = (const float*)d_in[1];  // [Z, E]
  const float* ctx = (const float*)d_in[2];   // [B, E]
  const float* Wm = (const float*)d_in[3];    // [E, E]

  float* outf = (float*)d_out;
  float* aligned = outf;                          // [B, E]   = 1228800
  float* outv = outf + (size_t)B_ * E_;           // [B, E]   = 1228800
  float* attn = outf + (size_t)2 * B_ * E_;       // [B, K, 1] = 20480
  float* amax = attn + (size_t)B_ * K_;           // [B]      = 4096 (as float)

  hipLaunchKernelGGL(map_kernel, dim3(B_ / BT), dim3(320), 0, stream,
                     ctx, Wm, aligned);
  hipLaunchKernelGGL(topk_attn_kernel, dim3(B_), dim3(NT), 0, stream,
                     sp_z, sp_w, aligned, outv, attn, amax);
}

// Round 7
// 1160.849 us; speedup vs baseline: 1.0496x; 1.0496x over previous
//
#include <hip/hip_runtime.h>
#include <math.h>

// Problem constants (from reference): B=4096, Z=50000, E=300, K=5
#define B_ 4096
#define Z_ 50000
#define E_ 300
#define K_ 5
#define NT 256   // threads for topk/attn kernel
#define BT 16    // batch tile for mapping kernel

// ---------------------------------------------------------------------------
// Kernel 1: aligned_ctx[b][e] = sum_j ctx[b][j] * W_map[e][j]   (ctx @ W^T)
// ---------------------------------------------------------------------------
__global__ __launch_bounds__(320) void map_kernel(const float* __restrict__ ctx,
                                                  const float* __restrict__ Wm,
                                                  float* __restrict__ aligned) {
  __shared__ __align__(16) float sctx[BT][E_];
  const int b0 = blockIdx.x * BT;
  for (int i = threadIdx.x; i < BT * E_; i += 320) {
    const int bb = i / E_;
    const int j = i - bb * E_;
    sctx[bb][j] = ctx[(size_t)(b0 + bb) * E_ + j];
  }
  __syncthreads();
  const int e = threadIdx.x;
  if (e < E_) {
    float acc[BT];
#pragma unroll
    for (int q = 0; q < BT; ++q) acc[q] = 0.f;
    const float4* wrow = reinterpret_cast<const float4*>(Wm + (size_t)e * E_);
    for (int j4 = 0; j4 < E_ / 4; ++j4) {
      const float4 w = wrow[j4];
#pragma unroll
      for (int q = 0; q < BT; ++q) {
        const float4 c = *reinterpret_cast<const float4*>(&sctx[q][j4 * 4]);
        acc[q] += c.x * w.x + c.y * w.y + c.z * w.z + c.w * w.w;
      }
    }
#pragma unroll
    for (int q = 0; q < BT; ++q) aligned[(size_t)(b0 + q) * E_ + e] = acc[q];
  }
}

// Branchless insert of (v, idx) into descending sorted 5-list tv/ti.
// Strict > : equal values keep the EARLIER (smaller) index first — matches
// jax.lax.top_k. Descending update order means no temporaries needed (each
// line reads only not-yet-updated entries).
#define INS5(v, idx)                                        \
  {                                                         \
    const float v_ = (v);                                   \
    const int i_ = (idx);                                   \
    const bool c4 = v_ > tv[4];                             \
    const bool c3 = v_ > tv[3];                             \
    const bool c2 = v_ > tv[2];                             \
    const bool c1 = v_ > tv[1];                             \
    const bool c0 = v_ > tv[0];                             \
    tv[4] = c4 ? (c3 ? tv[3] : v_) : tv[4];                 \
    ti[4] = c4 ? (c3 ? ti[3] : i_) : ti[4];                 \
    tv[3] = c3 ? (c2 ? tv[2] : v_) : tv[3];                 \
    ti[3] = c3 ? (c2 ? ti[2] : i_) : ti[3];                 \
    tv[2] = c2 ? (c1 ? tv[1] : v_) : tv[2];                 \
    ti[2] = c2 ? (c1 ? ti[1] : i_) : ti[2];                 \
    tv[1] = c1 ? (c0 ? tv[0] : v_) : tv[1];                 \
    ti[1] = c1 ? (c0 ? ti[0] : i_) : ti[1];                 \
    tv[0] = c0 ? v_ : tv[0];                                \
    ti[0] = c0 ? i_ : ti[0];                                \
  }

// ---------------------------------------------------------------------------
// Kernel 2 (fused): per row b: top-5 of sp_z[b], gather sp_w rows, scores,
// softmax, weighted sum, argmax. One 256-thread block per row.
// ---------------------------------------------------------------------------
__global__ __launch_bounds__(NT) void topk_attn_kernel(
    const float* __restrict__ sp_z, const float* __restrict__ sp_w,
    const float* __restrict__ aligned, float* __restrict__ outv,
    float* __restrict__ attn_out, float* __restrict__ amax_out) {
  const int b = blockIdx.x;
  const int tid = threadIdx.x;

  __shared__ __align__(16) float sal[E_];      // aligned_ctx row
  __shared__ float sval[NT * K_];              // per-thread top-5 values
  __shared__ int sidx[NT * K_];                // per-thread top-5 indices
  __shared__ float sw[K_][E_];                 // gathered topW rows
  __shared__ float sred[K_][4];                // per-wave score partials
  __shared__ float sattn[K_];                  // softmax weights

  // stage aligned_ctx row (covered by the first __syncthreads below)
  for (int e2 = tid; e2 < E_; e2 += NT) sal[e2] = aligned[(size_t)b * E_ + e2];

  // ---- per-thread streaming top-5: prefetched, branchless insert ----
  float tv[K_];
  int ti[K_];
#pragma unroll
  for (int p = 0; p < K_; ++p) { tv[p] = -INFINITY; ti[p] = 0x7fffffff; }

  const float4* __restrict__ rowz =
      reinterpret_cast<const float4*>(sp_z + (size_t)b * Z_);
  const int NC = Z_ / 4;  // 12500
  int c = tid;            // first load valid for all threads (tid < 256 < NC)
  float4 cur = rowz[c];
  while (true) {
    const int cn = c + NT;
    const bool more = (cn < NC);
    float4 nxt;
    if (more) nxt = rowz[cn];  // prefetch next chunk before compute
    const int base = c * 4;
    const float m4 = fmaxf(fmaxf(cur.x, cur.y), fmaxf(cur.z, cur.w));
    if (m4 > tv[K_ - 1]) {  // cheap pre-filter; inserts inside are branchless
      INS5(cur.x, base + 0);
      INS5(cur.y, base + 1);
      INS5(cur.z, base + 2);
      INS5(cur.w, base + 3);
    }
    if (!more) break;
    cur = nxt;
    c = cn;
  }
#pragma unroll
  for (int p = 0; p < K_; ++p) { sval[tid * K_ + p] = tv[p]; sidx[tid * K_ + p] = ti[p]; }
  __syncthreads();

  // ---- tree merge of sorted 5-lists (static register indexing only) ----
  for (int stride = NT / 2; stride >= 1; stride >>= 1) {
    if (tid < stride) {
      float av[K_], bv[K_];
      int ai[K_], bi[K_];
#pragma unroll
      for (int p = 0; p < K_; ++p) {
        av[p] = sval[tid * K_ + p]; ai[p] = sidx[tid * K_ + p];
        bv[p] = sval[(tid + stride) * K_ + p]; bi[p] = sidx[(tid + stride) * K_ + p];
      }
#pragma unroll
      for (int p = 0; p < K_; ++p) {
        const float v = bv[p]; const int i2 = bi[p];
        if (v > av[K_ - 1] || (v == av[K_ - 1] && i2 < ai[K_ - 1])) {
          av[K_ - 1] = v; ai[K_ - 1] = i2;
#pragma unroll
          for (int q = K_ - 1; q > 0; --q) {
            const bool swp = (av[q] > av[q - 1]) ||
                             (av[q] == av[q - 1] && ai[q] < ai[q - 1]);
            if (swp) {
              const float tf = av[q]; av[q] = av[q - 1]; av[q - 1] = tf;
              const int tt = ai[q]; ai[q] = ai[q - 1]; ai[q - 1] = tt;
            }
          }
        }
      }
#pragma unroll
      for (int q = 0; q < K_; ++q) { sval[tid * K_ + q] = av[q]; sidx[tid * K_ + q] = ai[q]; }
    }
    __syncthreads();
  }
  // final row top-5 now in sval[0..4] / sidx[0..4]

  // ---- gather topW rows + partial dot with aligned row (single pass) ----
  const float* __restrict__ wrow0 = sp_w + (size_t)sidx[0] * E_;
  const float* __restrict__ wrow1 = sp_w + (size_t)sidx[1] * E_;
  const float* __restrict__ wrow2 = sp_w + (size_t)sidx[2] * E_;
  const float* __restrict__ wrow3 = sp_w + (size_t)sidx[3] * E_;
  const float* __restrict__ wrow4 = sp_w + (size_t)sidx[4] * E_;

  float part[K_] = {0.f, 0.f, 0.f, 0.f, 0.f};
  for (int e2 = tid; e2 < E_; e2 += NT) {
    const float a = sal[e2];
    const float w0 = wrow0[e2], w1 = wrow1[e2], w2 = wrow2[e2],
                w3 = wrow3[e2], w4 = wrow4[e2];
    sw[0][e2] = w0; sw[1][e2] = w1; sw[2][e2] = w2; sw[3][e2] = w3; sw[4][e2] = w4;
    part[0] += w0 * a; part[1] += w1 * a; part[2] += w2 * a;
    part[3] += w3 * a; part[4] += w4 * a;
  }

  // ---- block reduce 5 scores ----
  const int lane = tid & 63;
  const int wv = tid >> 6;
#pragma unroll
  for (int k = 0; k < K_; ++k) {
    float p = part[k];
#pragma unroll
    for (int off = 32; off >= 1; off >>= 1) p += __shfl_down(p, off, 64);
    if (lane == 0) sred[k][wv] = p;
  }
  __syncthreads();

  if (tid == 0) {
    float sc[K_];
    float m = -INFINITY;
#pragma unroll
    for (int k = 0; k < K_; ++k) {
      sc[k] = sred[k][0] + sred[k][1] + sred[k][2] + sred[k][3];
      m = fmaxf(m, sc[k]);
    }
    float s = 0.f;
#pragma unroll
    for (int k = 0; k < K_; ++k) { sc[k] = expf(sc[k] - m); s += sc[k]; }
    const float inv = 1.f / s;
    int am = 0;
    float best = -INFINITY;
#pragma unroll
    for (int k = 0; k < K_; ++k) {
      const float a = sc[k] * inv;
      sattn[k] = a;
      attn_out[(size_t)b * K_ + k] = a;
      if (a > best) { best = a; am = k; }  // strict >: first max, like argmax
    }
    amax_out[b] = (float)am;
  }
  __syncthreads();

  // ---- out[b][e] = sum_k attn_k * topW[k][e] ----
  for (int e2 = tid; e2 < E_; e2 += NT) {
    float o = 0.f;
#pragma unroll
    for (int k = 0; k < K_; ++k) o += sattn[k] * sw[k][e2];
    outv[(size_t)b * E_ + e2] = o;
  }
}

// ---------------------------------------------------------------------------
extern "C" void kernel_launch(void* const* d_in, const int* in_sizes, int n_in,
                              void* d_out, int out_size, void* d_ws, size_t ws_size,
                              hipStream_t stream) {
  const float* sp_z = (const float*)d_in[0];  // [B, Z]
  const float* sp_w = (const float*)d_in[1];  // [Z, E]
  const float* ctx = (const float*)d_in[2];   // [B, E]
  const float* Wm = (const float*)d_in[3];    // [E, E]

  float* outf = (float*)d_out;
  float* aligned = outf;                          // [B, E]   = 1228800
  float* outv = outf + (size_t)B_ * E_;           // [B, E]   = 1228800
  float* attn = outf + (size_t)2 * B_ * E_;       // [B, K, 1] = 20480
  float* amax = attn + (size_t)B_ * K_;           // [B]      = 4096 (as float)

  hipLaunchKernelGGL(map_kernel, dim3(B_ / BT), dim3(320), 0, stream,
                     ctx, Wm, aligned);
  hipLaunchKernelGGL(topk_attn_kernel, dim3(B_), dim3(NT), 0, stream,
                     sp_z, sp_w, aligned, outv, attn, amax);
}